// Round 13
// baseline (70.484 us; speedup 1.0000x reference)
//
#include <hip/hip_runtime.h>
#include <hip/hip_bf16.h>
#include <stdint.h>

typedef __attribute__((ext_vector_type(8))) short short8;
typedef __bf16 bf16x8 __attribute__((ext_vector_type(8)));
typedef __attribute__((ext_vector_type(4))) float f32x4;

#define HID 128
#define NTILES 8   // 8 hid tiles of 16 -> 128 hidden units
#define KSTEPS 4   // 4 K-steps of 32 -> K=128

// ws layout (float index): [0,8192) afrag (short[16384], W as A-operand frags);
// [8192,8320) c; [8320,8448) w2; [8448] b2; [8512] atomic tail-chunk counter.
#define WS_C_F    8192
#define WS_W2_F   8320
#define WS_B2_F   8448
#define WS_CTR_F  8512

#define TP_BLOCKS   256
#define TP_WAVES    8
#define TP_THREADS  (TP_WAVES * 64)   // 512
#define TOTAL_TP_WAVES (TP_BLOCKS * TP_WAVES)   // 2048

#define SLOT_BYTES    8192            // one 16-node chunk (16 x 512B)
#define AFRAG_BYTES   32768
#define SMEM_BYTES    (AFRAG_BYTES + TP_WAVES * 2 * SLOT_BYTES)  // 163840 == full LDS

// ---------------- prep (grid=20 x 512): b0-2 heads, b3 c/w2/b2/ctr, b4-19 pack W frags
__global__ void prep_kernel(const float* __restrict__ node_hidden,
                            const float* __restrict__ h_glob,
                            const float* __restrict__ state,
                            const float* __restrict__ validity,
                            const float* __restrict__ W_hl1, const float* __restrict__ b_hl1,
                            const float* __restrict__ W_hl2, const float* __restrict__ b_hl2,
                            const float* __restrict__ W_in1, const float* __restrict__ b_in1,
                            const float* __restrict__ W_in2, const float* __restrict__ b_in2,
                            const float* __restrict__ W_ex1, const float* __restrict__ b_ex1,
                            const float* __restrict__ W_ex2, const float* __restrict__ b_ex2,
                            const float* __restrict__ W_tp1, const float* __restrict__ b_tp1,
                            const float* __restrict__ W_tp2, const float* __restrict__ b_tp2,
                            float* __restrict__ out, float* __restrict__ ws, int n)
{
    const int tid = threadIdx.x;
    const int b = blockIdx.x;

    if (b < 3) {
        __shared__ float feats[264];
        __shared__ float hpart[4][128];
        __shared__ float hidden[128];
        const float* W1 = (b == 0) ? W_hl1 : (b == 1 ? W_in1 : W_ex1);
        const float* b1 = (b == 0) ? b_hl1 : (b == 1 ? b_in1 : b_ex1);
        const float* W2 = (b == 0) ? W_hl2 : (b == 1 ? W_in2 : W_ex2);
        const float* b2 = (b == 0) ? b_hl2 : (b == 1 ? b_in2 : b_ex2);
        const int od    = (b == 0) ? 4 : (b == 1 ? 5 : 30);
        const int obase = (b == 0) ? 0 : (b == 1 ? 4 : 9);

        if (tid < 264) {
            float v;
            if (tid < 128)      v = node_hidden[tid];   // feats = [cur, h_glob, state]
            else if (tid < 256) v = h_glob[tid - 128];
            else                v = state[tid - 256];
            feats[tid] = v;
        }
        __syncthreads();
        {   // layer 1: output j, 4-way split over i (66 each)
            const int j = tid & 127, q = tid >> 7;
            float s = 0.f;
            for (int i = q * 66; i < q * 66 + 66; ++i) s += feats[i] * W1[i * 128 + j];
            hpart[q][j] = s;
        }
        __syncthreads();
        if (tid < 128) {
            float h = b1[tid] + hpart[0][tid] + hpart[1][tid] + hpart[2][tid] + hpart[3][tid];
            hidden[tid] = fmaxf(h, 0.f);
        }
        __syncthreads();
        if (tid < od) {
            float o = b2[tid];
            for (int i = 0; i < 128; ++i) o += hidden[i] * W2[i * od + tid];
            if (b == 2) o += logf(validity[tid]);
            out[obase + tid] = o;
        }
    } else if (b == 3) {
        // c = b_tp1 + h_glob @ W_tp1[0:128] + state @ W_tp1[256:264]; also w2, b2, ctr
        __shared__ float cpart[4][128];
        {
            const int j = tid & 127, q = tid >> 7;
            float s = 0.f;
            for (int i = q * 32; i < q * 32 + 32; ++i) s += h_glob[i] * W_tp1[i * HID + j];
            if (q == 3)
                for (int i = 0; i < 8; ++i) s += state[i] * W_tp1[(256 + i) * HID + j];
            cpart[q][j] = s;
        }
        __syncthreads();
        if (tid < 128) {
            ws[WS_C_F  + tid] = b_tp1[tid] + cpart[0][tid] + cpart[1][tid]
                                           + cpart[2][tid] + cpart[3][tid];
            ws[WS_W2_F + tid] = W_tp2[tid];
            if (tid == 0) {
                ws[WS_B2_F] = b_tp2[0];
                const int nChunks = (n + 15) >> 4;
                ((unsigned int*)ws)[WS_CTR_F] =
                    (unsigned int)((nChunks / TOTAL_TP_WAVES) * TOTAL_TP_WAVES);
            }
        }
    } else {
        // pack A-operand frags of W = W_tp1[128:256,:]: A[row=hid][k] = W_tp1[128+k][hid]
        // frag: row = lane&15, k = (lane>>4)*8 + j  (16B per lane per (t,s))
        short* afrag = (short*)ws;
        const int part = b - 4;                       // 0..15, 1024 entries each
        for (int idx = part * 1024 + tid; idx < part * 1024 + 1024; idx += 512) {
            const int k = idx >> 7, nn = idx & 127;   // source (k, hid)
            const int t = nn >> 4, cc = nn & 15;
            const int s = k >> 5, rr = k & 31;
            const int g = rr >> 3, j = rr & 7;
            const int lane = cc + (g << 4);
            afrag[(((t * KSTEPS + s) * 64 + lane) << 3) + j] =
                (short)__builtin_bit_cast(unsigned short, (__bf16)W_tp1[(128 + k) * HID + nn]);
        }
    }
}

// ---------------- teleport: DMA-staged, 8 waves (2/SIMD), depth-2 wave-private
// slots, full 160KB LDS. Uniform static share (12 chunks/wave, pipelined,
// counted vmcnt) + atomic-grab remainder tail (one grab per tail chunk, off
// the hot loop, unpipelined vmcnt(0)) -> removes the +-1-chunk (~6.5%) tail.
__launch_bounds__(TP_THREADS)
__global__ void teleport_kernel(const float* __restrict__ node_hidden, // n x 128
                                float* __restrict__ ws,                // weights + ctr
                                float* __restrict__ out,               // pre-offset (+39)
                                int n)
{
    __shared__ __align__(16) unsigned char smem[SMEM_BYTES];
    const int tid = threadIdx.x;

    const int lane = tid & 63;
    const int wave = tid >> 6;
    const int m  = lane & 15;     // node index within chunk (B col)
    const int g  = lane >> 4;     // k-group; C row-group (hid_local = g*4+r)
    const unsigned mx = (unsigned)(m & 7);        // read-side swizzle key
    const unsigned mrow = (unsigned)m * 512;      // node row base in slot

    {   // weights -> LDS (fully drained at the barrier; vmcnt counting starts at 0)
        const int4* wsv = (const int4*)ws;
        int4* sv = (int4*)smem;
        for (int i = tid; i < 2048; i += TP_THREADS) sv[i] = wsv[i];
    }
    // epilogue constants -> registers (drained by the same barrier)
    f32x4 cR[NTILES], wR[NTILES];
    #pragma unroll
    for (int t = 0; t < NTILES; ++t) {
        cR[t] = *(const f32x4*)(ws + WS_C_F  + t * 16 + g * 4);
        wR[t] = *(const f32x4*)(ws + WS_W2_F + t * 16 + g * 4);
    }
    const float bias2 = ws[WS_B2_F];
    unsigned int* ctr = (unsigned int*)ws + WS_CTR_F;
    __syncthreads();

    const short* afrag = (const short*)smem;

    unsigned char* p0 = smem + AFRAG_BYTES + wave * 2 * SLOT_BYTES;
    unsigned char* p1 = p0 + SLOT_BYTES;

    const int nChunks = (n + 15) >> 4;
    const int base = nChunks / TOTAL_TP_WAVES;          // uniform static share
    const int gw = blockIdx.x * TP_WAVES + wave;
    const int c0 = gw * base;
    const int c1 = c0 + base;

    // Stage one 16-node chunk into a slot: 8 x (64 lanes x 16B) coalesced DMA.
    // LDS linear offset o = k*1024 + lane*16 ; slot row = 2k + (lane>>5);
    // global source unit pre-swizzled: u' = (lane&31) ^ (row&7)  (T21).
#define STAGE(slot_, c_)                                                         \
    {                                                                            \
        _Pragma("unroll")                                                        \
        for (int k_ = 0; k_ < 8; ++k_) {                                         \
            const int row_ = 2 * k_ + (lane >> 5);                               \
            const int grow_ = min((c_) * 16 + row_, n - 1);                      \
            const unsigned su_ = ((unsigned)(lane & 31)) ^ ((unsigned)(row_ & 7));\
            const unsigned char* src_ = (const unsigned char*)node_hidden        \
                                        + (size_t)grow_ * 512 + (su_ << 4);      \
            __builtin_amdgcn_global_load_lds(                                    \
                (const __attribute__((address_space(1))) unsigned int*)src_,     \
                (__attribute__((address_space(3))) unsigned int*)(slot_ + k_ * 1024), \
                16, 0, 0);                                                       \
        }                                                                        \
    }

    // Consume the chunk in buf_ (read+convert, MFMA, epilogue, store).
#define COMPUTE_CHUNK(buf_, c_)                                                  \
    {                                                                            \
        bf16x8 nd[KSTEPS];                                                       \
        _Pragma("unroll")                                                        \
        for (int s = 0; s < KSTEPS; ++s) {                                       \
            const unsigned u0 = (((unsigned)(s * 8 + g * 2))     ^ mx) << 4;     \
            const unsigned u1 = (((unsigned)(s * 8 + g * 2 + 1)) ^ mx) << 4;     \
            const float4 fa = *(const float4*)((buf_) + mrow + u0);              \
            const float4 fb = *(const float4*)((buf_) + mrow + u1);              \
            bf16x8 a;                                                            \
            a[0] = (__bf16)fa.x; a[1] = (__bf16)fa.y;                            \
            a[2] = (__bf16)fa.z; a[3] = (__bf16)fa.w;                            \
            a[4] = (__bf16)fb.x; a[5] = (__bf16)fb.y;                            \
            a[6] = (__bf16)fb.z; a[7] = (__bf16)fb.w;                            \
            nd[s] = a;                                                           \
        }                                                                        \
        float sr = 0.f;                                                          \
        _Pragma("unroll")                                                        \
        for (int t = 0; t < NTILES; ++t) {                                       \
            f32x4 acc = (f32x4){0.f, 0.f, 0.f, 0.f};                             \
            _Pragma("unroll")                                                    \
            for (int s = 0; s < KSTEPS; ++s) {                                   \
                const short8 wv = *(const short8*)&afrag[(((t * KSTEPS + s) * 64 + lane) << 3)]; \
                const bf16x8 wf = __builtin_bit_cast(bf16x8, wv);                \
                acc = __builtin_amdgcn_mfma_f32_16x16x32_bf16(wf, nd[s], acc, 0, 0, 0); \
            }                                                                    \
            float h0 = acc[0] + cR[t][0], h1 = acc[1] + cR[t][1];                \
            float h2 = acc[2] + cR[t][2], h3 = acc[3] + cR[t][3];                \
            h0 = h0 > 0.f ? h0 : 0.f;  h1 = h1 > 0.f ? h1 : 0.f;                 \
            h2 = h2 > 0.f ? h2 : 0.f;  h3 = h3 > 0.f ? h3 : 0.f;                 \
            sr += h0 * wR[t][0] + h1 * wR[t][1] + h2 * wR[t][2] + h3 * wR[t][3]; \
        }                                                                        \
        sr += __shfl_xor(sr, 16, 64);                                            \
        sr += __shfl_xor(sr, 32, 64);                                            \
        if (lane < 16) {                                                         \
            const int o_ = (c_) * 16 + lane;                                     \
            if (o_ < n) out[o_] = sr + bias2;                                    \
        }                                                                        \
    }

    // ---- static pipelined share (uniform 'base' chunks per wave)
    {
        STAGE(p0, c0);
        if (c0 + 1 < c1) STAGE(p1, c0 + 1);

        for (int c = c0; c < c1; ++c) {
            if (c == c1 - 1)      { asm volatile("s_waitcnt vmcnt(0)"  ::: "memory"); }
            else if (c == c0)     { asm volatile("s_waitcnt vmcnt(8)"  ::: "memory"); }
            else if (c == c0 + 1) { asm volatile("s_waitcnt vmcnt(9)"  ::: "memory"); }
            else                  { asm volatile("s_waitcnt vmcnt(10)" ::: "memory"); }

            // pin: slot ds_reads issue before re-staging the same slot
            if (c + 2 < c1) {
                COMPUTE_CHUNK(p0, c);
                __builtin_amdgcn_sched_barrier(0);
                STAGE(p0, c + 2);
            } else {
                COMPUTE_CHUNK(p0, c);
            }
            unsigned char* tmp = p0; p0 = p1; p1 = tmp;
        }
    }

    // ---- remainder tail: one atomic grab per chunk (off the hot loop);
    // unpipelined (vmcnt(0)) — only ~0.2 chunks/wave on average.
    for (;;) {
        int pc = 0;
        if (lane == 0) pc = (int)atomicAdd(ctr, 1u);
        pc = __shfl(pc, 0, 64);
        if (pc >= nChunks) break;
        STAGE(p0, pc);
        asm volatile("s_waitcnt vmcnt(0)" ::: "memory");
        COMPUTE_CHUNK(p0, pc);
    }
#undef COMPUTE_CHUNK
#undef STAGE
}

extern "C" void kernel_launch(void* const* d_in, const int* in_sizes, int n_in,
                              void* d_out, int out_size, void* d_ws, size_t ws_size,
                              hipStream_t stream) {
    const float* node_hidden = (const float*)d_in[0];
    const float* h_glob      = (const float*)d_in[1];
    const float* state       = (const float*)d_in[2];
    const float* validity    = (const float*)d_in[3];
    const float* W_hl1 = (const float*)d_in[4];  const float* b_hl1 = (const float*)d_in[5];
    const float* W_hl2 = (const float*)d_in[6];  const float* b_hl2 = (const float*)d_in[7];
    const float* W_in1 = (const float*)d_in[8];  const float* b_in1 = (const float*)d_in[9];
    const float* W_in2 = (const float*)d_in[10]; const float* b_in2 = (const float*)d_in[11];
    const float* W_ex1 = (const float*)d_in[12]; const float* b_ex1 = (const float*)d_in[13];
    const float* W_ex2 = (const float*)d_in[14]; const float* b_ex2 = (const float*)d_in[15];
    const float* W_tp1 = (const float*)d_in[16]; const float* b_tp1 = (const float*)d_in[17];
    const float* W_tp2 = (const float*)d_in[18]; const float* b_tp2 = (const float*)d_in[19];

    float* out = (float*)d_out;
    float* ws  = (float*)d_ws;
    const int n = in_sizes[0] / HID;   // 400000

    prep_kernel<<<20, 512, 0, stream>>>(node_hidden, h_glob, state, validity,
                                        W_hl1, b_hl1, W_hl2, b_hl2,
                                        W_in1, b_in1, W_in2, b_in2,
                                        W_ex1, b_ex1, W_ex2, b_ex2,
                                        W_tp1, b_tp1, W_tp2, b_tp2,
                                        out, ws, n);
    teleport_kernel<<<TP_BLOCKS, TP_THREADS, 0, stream>>>(node_hidden, ws, out + 39, n);
}

// Round 14
// 45.206 us; speedup vs baseline: 1.5592x; 1.5592x over previous
//
#include <hip/hip_runtime.h>
#include <hip/hip_bf16.h>
#include <stdint.h>

typedef __attribute__((ext_vector_type(8))) short short8;
typedef __bf16 bf16x8 __attribute__((ext_vector_type(8)));
typedef __attribute__((ext_vector_type(4))) float f32x4;

#define HID 128
#define NTILES 8   // 8 hid tiles of 16 -> 128 hidden units
#define KSTEPS 4   // 4 K-steps of 32 -> K=128

// ws layout (float index): [0,8192) afrag (short[16384], W as A-operand frags);
// [8192,8320) c; [8320,8448) w2; [8448] b2.
#define WS_C_F    8192
#define WS_W2_F   8320
#define WS_B2_F   8448

#define TP_BLOCKS   256
#define TP_WAVES    8
#define TP_THREADS  (TP_WAVES * 64)   // 512
#define TOTAL_TP_WAVES (TP_BLOCKS * TP_WAVES)   // 2048

// weighted static split: waves of the 3 head blocks (gw<24) get 3 units,
// all others 12 -> head waves ~3 chunks, normal ~12.3
#define HEAD_WAVES 24
#define HW_U 3
#define NW_U 12
#define TOTAL_U (HEAD_WAVES * HW_U + (TOTAL_TP_WAVES - HEAD_WAVES) * NW_U)  // 24360

#define SLOT_BYTES    8192            // one 16-node chunk (16 x 512B)
#define AFRAG_BYTES   32768
#define SMEM_BYTES    (AFRAG_BYTES + TP_WAVES * 2 * SLOT_BYTES)  // 163840 == full LDS

// ---------------- prep (grid=17 x 512): b0 c/w2/b2, b1-16 pack W frags
__global__ void prep_kernel(const float* __restrict__ h_glob,
                            const float* __restrict__ state,
                            const float* __restrict__ W_tp1, const float* __restrict__ b_tp1,
                            const float* __restrict__ W_tp2, const float* __restrict__ b_tp2,
                            float* __restrict__ ws)
{
    const int tid = threadIdx.x;
    const int b = blockIdx.x;

    if (b == 0) {
        // c = b_tp1 + h_glob @ W_tp1[0:128] + state @ W_tp1[256:264]; also w2, b2
        __shared__ float cpart[4][128];
        {
            const int j = tid & 127, q = tid >> 7;
            float s = 0.f;
            for (int i = q * 32; i < q * 32 + 32; ++i) s += h_glob[i] * W_tp1[i * HID + j];
            if (q == 3)
                for (int i = 0; i < 8; ++i) s += state[i] * W_tp1[(256 + i) * HID + j];
            cpart[q][j] = s;
        }
        __syncthreads();
        if (tid < 128) {
            ws[WS_C_F  + tid] = b_tp1[tid] + cpart[0][tid] + cpart[1][tid]
                                           + cpart[2][tid] + cpart[3][tid];
            ws[WS_W2_F + tid] = W_tp2[tid];
            if (tid == 0) ws[WS_B2_F] = b_tp2[0];
        }
    } else {
        // pack A-operand frags of W = W_tp1[128:256,:]: A[row=hid][k] = W_tp1[128+k][hid]
        // frag: row = lane&15, k = (lane>>4)*8 + j  (16B per lane per (t,s))
        short* afrag = (short*)ws;
        const int part = b - 1;                       // 0..15, 1024 entries each
        for (int idx = part * 1024 + tid; idx < part * 1024 + 1024; idx += 512) {
            const int k = idx >> 7, nn = idx & 127;   // source (k, hid)
            const int t = nn >> 4, cc = nn & 15;
            const int s = k >> 5, rr = k & 31;
            const int g = rr >> 3, j = rr & 7;
            const int lane = cc + (g << 4);
            afrag[(((t * KSTEPS + s) * 64 + lane) << 3) + j] =
                (short)__builtin_bit_cast(unsigned short, (__bf16)W_tp1[(128 + k) * HID + nn]);
        }
    }
}

// ---------------- teleport: R12 core (DMA-staged, 8 waves 2/SIMD, depth-2
// wave-private slots, full 160KB LDS, counted vmcnt {8,9,10,0}).
// Blocks 0-2 additionally compute one output head each BEFORE the prologue
// (their global loads drain at the pre-main barrier) and carry a reduced
// static chunk share via the weighted partition.
__launch_bounds__(TP_THREADS)
__global__ void teleport_kernel(const float* __restrict__ node_hidden, // n x 128
                                const float* __restrict__ h_glob,
                                const float* __restrict__ state,
                                const float* __restrict__ validity,
                                const float* __restrict__ W_hl1, const float* __restrict__ b_hl1,
                                const float* __restrict__ W_hl2, const float* __restrict__ b_hl2,
                                const float* __restrict__ W_in1, const float* __restrict__ b_in1,
                                const float* __restrict__ W_in2, const float* __restrict__ b_in2,
                                const float* __restrict__ W_ex1, const float* __restrict__ b_ex1,
                                const float* __restrict__ W_ex2, const float* __restrict__ b_ex2,
                                const float* __restrict__ ws,          // packed weights
                                float* __restrict__ out,               // base (heads at [0,39))
                                int n)
{
    __shared__ __align__(16) unsigned char smem[SMEM_BYTES];
    const int tid = threadIdx.x;

    const int lane = tid & 63;
    const int wave = tid >> 6;
    const int m  = lane & 15;     // node index within chunk (B col)
    const int g  = lane >> 4;     // k-group; C row-group (hid_local = g*4+r)
    const unsigned mx = (unsigned)(m & 7);        // read-side swizzle key
    const unsigned mrow = (unsigned)m * 512;      // node row base in slot

    // ---- heads on blocks 0-2 (scratch aliases the slot area; done before staging)
    if (blockIdx.x < 3) {
        float* feats  = (float*)(smem + AFRAG_BYTES);        // 264
        float* hpart  = feats + 264;                         // 4*128
        float* hidden = hpart + 512;                         // 128
        const int b = blockIdx.x;
        const float* W1 = (b == 0) ? W_hl1 : (b == 1 ? W_in1 : W_ex1);
        const float* b1 = (b == 0) ? b_hl1 : (b == 1 ? b_in1 : b_ex1);
        const float* W2 = (b == 0) ? W_hl2 : (b == 1 ? W_in2 : W_ex2);
        const float* b2 = (b == 0) ? b_hl2 : (b == 1 ? b_in2 : b_ex2);
        const int od    = (b == 0) ? 4 : (b == 1 ? 5 : 30);
        const int obase = (b == 0) ? 0 : (b == 1 ? 4 : 9);

        if (tid < 264) {
            float v;
            if (tid < 128)      v = node_hidden[tid];   // feats = [cur, h_glob, state]
            else if (tid < 256) v = h_glob[tid - 128];
            else                v = state[tid - 256];
            feats[tid] = v;
        }
        __syncthreads();
        {   // layer 1: output j, 4-way split over i (66 each)
            const int j = tid & 127, q = tid >> 7;
            float s = 0.f;
            for (int i = q * 66; i < q * 66 + 66; ++i) s += feats[i] * W1[i * 128 + j];
            hpart[q * 128 + j] = s;
        }
        __syncthreads();
        if (tid < 128) {
            float h = b1[tid] + hpart[tid] + hpart[128 + tid] + hpart[256 + tid] + hpart[384 + tid];
            hidden[tid] = fmaxf(h, 0.f);
        }
        __syncthreads();
        if (tid < od) {
            float o = b2[tid];
            for (int i = 0; i < 128; ++i) o += hidden[i] * W2[i * od + tid];
            if (b == 2) o += logf(validity[tid]);
            out[obase + tid] = o;
        }
        __syncthreads();
    }

    {   // weights -> LDS (fully drained at the barrier; vmcnt counting starts at 0)
        const int4* wsv = (const int4*)ws;
        int4* sv = (int4*)smem;
        for (int i = tid; i < 2048; i += TP_THREADS) sv[i] = wsv[i];
    }
    // epilogue constants -> registers (drained by the same barrier)
    f32x4 cR[NTILES], wR[NTILES];
    #pragma unroll
    for (int t = 0; t < NTILES; ++t) {
        cR[t] = *(const f32x4*)(ws + WS_C_F  + t * 16 + g * 4);
        wR[t] = *(const f32x4*)(ws + WS_W2_F + t * 16 + g * 4);
    }
    const float bias2 = ws[WS_B2_F];
    __syncthreads();

    const short* afrag = (const short*)smem;
    float* tout = out + 39;

    unsigned char* p0 = smem + AFRAG_BYTES + wave * 2 * SLOT_BYTES;
    unsigned char* p1 = p0 + SLOT_BYTES;

    const int nChunks = (n + 15) >> 4;
    const int gw = blockIdx.x * TP_WAVES + wave;
    const long long cumA = (gw < HEAD_WAVES)
        ? (long long)gw * HW_U
        : (long long)HEAD_WAVES * HW_U + (long long)(gw - HEAD_WAVES) * NW_U;
    const long long cumB = (gw + 1 <= HEAD_WAVES)
        ? (long long)(gw + 1) * HW_U
        : (long long)HEAD_WAVES * HW_U + (long long)(gw + 1 - HEAD_WAVES) * NW_U;
    const int c0 = (int)(cumA * nChunks / TOTAL_U);
    const int c1 = (int)(cumB * nChunks / TOTAL_U);

    // Stage one 16-node chunk into a slot: 8 x (64 lanes x 16B) coalesced DMA.
    // LDS linear offset o = k*1024 + lane*16 ; slot row = 2k + (lane>>5);
    // global source unit pre-swizzled: u' = (lane&31) ^ (row&7)  (T21).
#define STAGE(slot_, c_)                                                         \
    {                                                                            \
        _Pragma("unroll")                                                        \
        for (int k_ = 0; k_ < 8; ++k_) {                                         \
            const int row_ = 2 * k_ + (lane >> 5);                               \
            const int grow_ = min((c_) * 16 + row_, n - 1);                      \
            const unsigned su_ = ((unsigned)(lane & 31)) ^ ((unsigned)(row_ & 7));\
            const unsigned char* src_ = (const unsigned char*)node_hidden        \
                                        + (size_t)grow_ * 512 + (su_ << 4);      \
            __builtin_amdgcn_global_load_lds(                                    \
                (const __attribute__((address_space(1))) unsigned int*)src_,     \
                (__attribute__((address_space(3))) unsigned int*)(slot_ + k_ * 1024), \
                16, 0, 0);                                                       \
        }                                                                        \
    }

    if (c0 < c1) {
        STAGE(p0, c0);
        if (c0 + 1 < c1) STAGE(p1, c0 + 1);

        for (int c = c0; c < c1; ++c) {
            if (c == c1 - 1)      { asm volatile("s_waitcnt vmcnt(0)"  ::: "memory"); }
            else if (c == c0)     { asm volatile("s_waitcnt vmcnt(8)"  ::: "memory"); }
            else if (c == c0 + 1) { asm volatile("s_waitcnt vmcnt(9)"  ::: "memory"); }
            else                  { asm volatile("s_waitcnt vmcnt(10)" ::: "memory"); }

            // read + convert this chunk's node fragments (swizzled units)
            bf16x8 nd[KSTEPS];
            #pragma unroll
            for (int s = 0; s < KSTEPS; ++s) {
                const unsigned u0 = (((unsigned)(s * 8 + g * 2))     ^ mx) << 4;
                const unsigned u1 = (((unsigned)(s * 8 + g * 2 + 1)) ^ mx) << 4;
                const float4 fa = *(const float4*)(p0 + mrow + u0);
                const float4 fb = *(const float4*)(p0 + mrow + u1);
                bf16x8 a;
                a[0] = (__bf16)fa.x; a[1] = (__bf16)fa.y; a[2] = (__bf16)fa.z; a[3] = (__bf16)fa.w;
                a[4] = (__bf16)fb.x; a[5] = (__bf16)fb.y; a[6] = (__bf16)fb.z; a[7] = (__bf16)fb.w;
                nd[s] = a;
            }
            // pin: all slot ds_reads issue before re-staging the same slot
            __builtin_amdgcn_sched_barrier(0);
            if (c + 2 < c1) STAGE(p0, c + 2);

            float sr = 0.f;
            #pragma unroll
            for (int t = 0; t < NTILES; ++t) {
                f32x4 acc = (f32x4){0.f, 0.f, 0.f, 0.f};
                #pragma unroll
                for (int s = 0; s < KSTEPS; ++s) {
                    const short8 wv = *(const short8*)&afrag[(((t * KSTEPS + s) * 64 + lane) << 3)];
                    const bf16x8 wf = __builtin_bit_cast(bf16x8, wv);
                    acc = __builtin_amdgcn_mfma_f32_16x16x32_bf16(wf, nd[s], acc, 0, 0, 0);
                }
                float h0 = acc[0] + cR[t][0], h1 = acc[1] + cR[t][1];
                float h2 = acc[2] + cR[t][2], h3 = acc[3] + cR[t][3];
                h0 = h0 > 0.f ? h0 : 0.f;  h1 = h1 > 0.f ? h1 : 0.f;
                h2 = h2 > 0.f ? h2 : 0.f;  h3 = h3 > 0.f ? h3 : 0.f;
                sr += h0 * wR[t][0] + h1 * wR[t][1] + h2 * wR[t][2] + h3 * wR[t][3];
            }

            // sum across the 4 g-groups (lanes differing in bits 4,5)
            sr += __shfl_xor(sr, 16, 64);
            sr += __shfl_xor(sr, 32, 64);

            // lanes 0..15 store 16 contiguous dwords (64B per wave)
            if (lane < 16) {
                const int o = c * 16 + lane;
                if (o < n) tout[o] = sr + bias2;
            }

            unsigned char* tmp = p0; p0 = p1; p1 = tmp;
        }
    }
#undef STAGE
}

extern "C" void kernel_launch(void* const* d_in, const int* in_sizes, int n_in,
                              void* d_out, int out_size, void* d_ws, size_t ws_size,
                              hipStream_t stream) {
    const float* node_hidden = (const float*)d_in[0];
    const float* h_glob      = (const float*)d_in[1];
    const float* state       = (const float*)d_in[2];
    const float* validity    = (const float*)d_in[3];
    const float* W_hl1 = (const float*)d_in[4];  const float* b_hl1 = (const float*)d_in[5];
    const float* W_hl2 = (const float*)d_in[6];  const float* b_hl2 = (const float*)d_in[7];
    const float* W_in1 = (const float*)d_in[8];  const float* b_in1 = (const float*)d_in[9];
    const float* W_in2 = (const float*)d_in[10]; const float* b_in2 = (const float*)d_in[11];
    const float* W_ex1 = (const float*)d_in[12]; const float* b_ex1 = (const float*)d_in[13];
    const float* W_ex2 = (const float*)d_in[14]; const float* b_ex2 = (const float*)d_in[15];
    const float* W_tp1 = (const float*)d_in[16]; const float* b_tp1 = (const float*)d_in[17];
    const float* W_tp2 = (const float*)d_in[18]; const float* b_tp2 = (const float*)d_in[19];

    float* out = (float*)d_out;
    float* ws  = (float*)d_ws;
    const int n = in_sizes[0] / HID;   // 400000

    prep_kernel<<<17, 512, 0, stream>>>(h_glob, state, W_tp1, b_tp1, W_tp2, b_tp2, ws);
    teleport_kernel<<<TP_BLOCKS, TP_THREADS, 0, stream>>>(node_hidden, h_glob, state, validity,
                                                          W_hl1, b_hl1, W_hl2, b_hl2,
                                                          W_in1, b_in1, W_in2, b_in2,
                                                          W_ex1, b_ex1, W_ex2, b_ex2,
                                                          ws, out, n);
}

// Round 15
// 43.535 us; speedup vs baseline: 1.6190x; 1.0384x over previous
//
#include <hip/hip_runtime.h>
#include <hip/hip_bf16.h>
#include <stdint.h>

typedef __attribute__((ext_vector_type(8))) short short8;
typedef __bf16 bf16x8 __attribute__((ext_vector_type(8)));
typedef __attribute__((ext_vector_type(4))) float f32x4;

#define HID 128
#define NTILES 8   // 8 hid tiles of 16 -> 128 hidden units
#define KSTEPS 4   // 4 K-steps of 32 -> K=128

#define TP_BLOCKS   256
#define TP_WAVES    8
#define TP_THREADS  (TP_WAVES * 64)   // 512
#define TOTAL_TP_WAVES (TP_BLOCKS * TP_WAVES)   // 2048

// weighted static split: waves of the 3 head blocks (gw<24) get 3 units,
// all others 12 -> head waves ~3 chunks, normal ~12.3
#define HEAD_WAVES 24
#define HW_U 3
#define NW_U 12
#define TOTAL_U (HEAD_WAVES * HW_U + (TOTAL_TP_WAVES - HEAD_WAVES) * NW_U)  // 24360

#define SLOT_BYTES    8192            // one 16-node chunk (16 x 512B)
#define AFRAG_BYTES   32768
#define SMEM_BYTES    (AFRAG_BYTES + TP_WAVES * 2 * SLOT_BYTES)  // 163840 == full LDS

// ---------------- single fused kernel: per-block prologue packs W fragments
// (direct from W_tp1, L2-resident after first touch) + computes c/w2; blocks
// 0-2 additionally compute the three small heads. Main loop = R12/R14 core:
// DMA-staged (global_load_lds), 8 waves (2/SIMD), depth-2 wave-private slots,
// full 160KB LDS, counted vmcnt {8,9,10,0} (never draining mid-loop).
__launch_bounds__(TP_THREADS)
__global__ void teleport_kernel(const float* __restrict__ node_hidden, // n x 128
                                const float* __restrict__ h_glob,
                                const float* __restrict__ state,
                                const float* __restrict__ validity,
                                const float* __restrict__ W_hl1, const float* __restrict__ b_hl1,
                                const float* __restrict__ W_hl2, const float* __restrict__ b_hl2,
                                const float* __restrict__ W_in1, const float* __restrict__ b_in1,
                                const float* __restrict__ W_in2, const float* __restrict__ b_in2,
                                const float* __restrict__ W_ex1, const float* __restrict__ b_ex1,
                                const float* __restrict__ W_ex2, const float* __restrict__ b_ex2,
                                const float* __restrict__ W_tp1, const float* __restrict__ b_tp1,
                                const float* __restrict__ W_tp2, const float* __restrict__ b_tp2,
                                float* __restrict__ out,               // base (heads at [0,39))
                                int n)
{
    __shared__ __align__(16) unsigned char smem[SMEM_BYTES];
    const int tid = threadIdx.x;

    const int lane = tid & 63;
    const int wave = tid >> 6;
    const int m  = lane & 15;     // node index within chunk (B col)
    const int g  = lane >> 4;     // k-group; C row-group (hid_local = g*4+r)
    const unsigned mx = (unsigned)(m & 7);        // read-side swizzle key
    const unsigned mrow = (unsigned)m * 512;      // node row base in slot

    short* afrag_w = (short*)smem;                       // [0, 32768)
    float* scr     = (float*)(smem + AFRAG_BYTES);       // prologue scratch (slot area)

    // ---- heads on blocks 0-2 (scratch aliases the slot area; done before staging)
    if (blockIdx.x < 3) {
        float* feats  = scr;                 // 264
        float* hpart  = feats + 264;         // 4*128
        float* hidden = hpart + 512;         // 128
        const int b = blockIdx.x;
        const float* W1 = (b == 0) ? W_hl1 : (b == 1 ? W_in1 : W_ex1);
        const float* b1 = (b == 0) ? b_hl1 : (b == 1 ? b_in1 : b_ex1);
        const float* W2 = (b == 0) ? W_hl2 : (b == 1 ? W_in2 : W_ex2);
        const float* b2 = (b == 0) ? b_hl2 : (b == 1 ? b_in2 : b_ex2);
        const int od    = (b == 0) ? 4 : (b == 1 ? 5 : 30);
        const int obase = (b == 0) ? 0 : (b == 1 ? 4 : 9);

        if (tid < 264) {
            float v;
            if (tid < 128)      v = node_hidden[tid];   // feats = [cur, h_glob, state]
            else if (tid < 256) v = h_glob[tid - 128];
            else                v = state[tid - 256];
            feats[tid] = v;
        }
        __syncthreads();
        {   // layer 1: output j, 4-way split over i (66 each)
            const int j = tid & 127, q = tid >> 7;
            float s = 0.f;
            for (int i = q * 66; i < q * 66 + 66; ++i) s += feats[i] * W1[i * 128 + j];
            hpart[q * 128 + j] = s;
        }
        __syncthreads();
        if (tid < 128) {
            float h = b1[tid] + hpart[tid] + hpart[128 + tid] + hpart[256 + tid] + hpart[384 + tid];
            hidden[tid] = fmaxf(h, 0.f);
        }
        __syncthreads();
        if (tid < od) {
            float o = b2[tid];
            for (int i = 0; i < 128; ++i) o += hidden[i] * W2[i * od + tid];
            if (b == 2) o += logf(validity[tid]);
            out[obase + tid] = o;
        }
        __syncthreads();
    }

    // ---- pack A-operand frags of W = W_tp1[128:256,:] directly into LDS.
    // A[row=hid][k] = W_tp1[128+k][hid]; frag: row = lane&15, k = (lane>>4)*8 + j.
    // W_tp1 (135KB) is L2-resident after first touch per XCD -> cheap re-reads.
    for (int idx = tid; idx < HID * HID; idx += TP_THREADS) {
        const int k = idx >> 7, nn = idx & 127;   // source (k, hid)
        const int t = nn >> 4, cc = nn & 15;
        const int s = k >> 5, rr = k & 31;
        const int g2 = rr >> 3, j = rr & 7;
        const int ln = cc + (g2 << 4);
        afrag_w[(((t * KSTEPS + s) * 64 + ln) << 3) + j] =
            (short)__builtin_bit_cast(unsigned short, (__bf16)W_tp1[(128 + k) * HID + nn]);
    }
    // ---- c = b_tp1 + h_glob @ W_tp1[0:128] + state @ W_tp1[256:264] (4-way split)
    {
        const int j = tid & 127, q = tid >> 7;
        float s = 0.f;
        for (int i = q * 32; i < q * 32 + 32; ++i) s += h_glob[i] * W_tp1[i * HID + j];
        if (q == 3)
            for (int i = 0; i < 8; ++i) s += state[i] * W_tp1[(256 + i) * HID + j];
        scr[q * 128 + j] = s;
    }
    __syncthreads();
    if (tid < 128)
        scr[512 + tid] = b_tp1[tid] + scr[tid] + scr[128 + tid] + scr[256 + tid] + scr[384 + tid];
    __syncthreads();

    // epilogue constants -> registers (c from LDS scratch, w2/b2 from global)
    f32x4 cR[NTILES], wR[NTILES];
    #pragma unroll
    for (int t = 0; t < NTILES; ++t) {
        cR[t] = *(const f32x4*)(scr + 512 + t * 16 + g * 4);
        wR[t] = *(const f32x4*)(W_tp2 + t * 16 + g * 4);
    }
    const float bias2 = b_tp2[0];
    // all prologue VMEM drains here; scratch reads complete before slots reused
    __syncthreads();

    const short* afrag = (const short*)smem;
    float* tout = out + 39;

    unsigned char* p0 = smem + AFRAG_BYTES + wave * 2 * SLOT_BYTES;
    unsigned char* p1 = p0 + SLOT_BYTES;

    const int nChunks = (n + 15) >> 4;
    const int gw = blockIdx.x * TP_WAVES + wave;
    const long long cumA = (gw < HEAD_WAVES)
        ? (long long)gw * HW_U
        : (long long)HEAD_WAVES * HW_U + (long long)(gw - HEAD_WAVES) * NW_U;
    const long long cumB = (gw + 1 <= HEAD_WAVES)
        ? (long long)(gw + 1) * HW_U
        : (long long)HEAD_WAVES * HW_U + (long long)(gw + 1 - HEAD_WAVES) * NW_U;
    const int c0 = (int)(cumA * nChunks / TOTAL_U);
    const int c1 = (int)(cumB * nChunks / TOTAL_U);

    // Stage one 16-node chunk into a slot: 8 x (64 lanes x 16B) coalesced DMA.
    // LDS linear offset o = k*1024 + lane*16 ; slot row = 2k + (lane>>5);
    // global source unit pre-swizzled: u' = (lane&31) ^ (row&7)  (T21).
#define STAGE(slot_, c_)                                                         \
    {                                                                            \
        _Pragma("unroll")                                                        \
        for (int k_ = 0; k_ < 8; ++k_) {                                         \
            const int row_ = 2 * k_ + (lane >> 5);                               \
            const int grow_ = min((c_) * 16 + row_, n - 1);                      \
            const unsigned su_ = ((unsigned)(lane & 31)) ^ ((unsigned)(row_ & 7));\
            const unsigned char* src_ = (const unsigned char*)node_hidden        \
                                        + (size_t)grow_ * 512 + (su_ << 4);      \
            __builtin_amdgcn_global_load_lds(                                    \
                (const __attribute__((address_space(1))) unsigned int*)src_,     \
                (__attribute__((address_space(3))) unsigned int*)(slot_ + k_ * 1024), \
                16, 0, 0);                                                       \
        }                                                                        \
    }

    if (c0 < c1) {
        STAGE(p0, c0);
        if (c0 + 1 < c1) STAGE(p1, c0 + 1);

        for (int c = c0; c < c1; ++c) {
            if (c == c1 - 1)      { asm volatile("s_waitcnt vmcnt(0)"  ::: "memory"); }
            else if (c == c0)     { asm volatile("s_waitcnt vmcnt(8)"  ::: "memory"); }
            else if (c == c0 + 1) { asm volatile("s_waitcnt vmcnt(9)"  ::: "memory"); }
            else                  { asm volatile("s_waitcnt vmcnt(10)" ::: "memory"); }

            // read + convert this chunk's node fragments (swizzled units)
            bf16x8 nd[KSTEPS];
            #pragma unroll
            for (int s = 0; s < KSTEPS; ++s) {
                const unsigned u0 = (((unsigned)(s * 8 + g * 2))     ^ mx) << 4;
                const unsigned u1 = (((unsigned)(s * 8 + g * 2 + 1)) ^ mx) << 4;
                const float4 fa = *(const float4*)(p0 + mrow + u0);
                const float4 fb = *(const float4*)(p0 + mrow + u1);
                bf16x8 a;
                a[0] = (__bf16)fa.x; a[1] = (__bf16)fa.y; a[2] = (__bf16)fa.z; a[3] = (__bf16)fa.w;
                a[4] = (__bf16)fb.x; a[5] = (__bf16)fb.y; a[6] = (__bf16)fb.z; a[7] = (__bf16)fb.w;
                nd[s] = a;
            }
            // pin: all slot ds_reads issue before re-staging the same slot
            __builtin_amdgcn_sched_barrier(0);
            if (c + 2 < c1) STAGE(p0, c + 2);

            float sr = 0.f;
            #pragma unroll
            for (int t = 0; t < NTILES; ++t) {
                f32x4 acc = (f32x4){0.f, 0.f, 0.f, 0.f};
                #pragma unroll
                for (int s = 0; s < KSTEPS; ++s) {
                    const short8 wv = *(const short8*)&afrag[(((t * KSTEPS + s) * 64 + lane) << 3)];
                    const bf16x8 wf = __builtin_bit_cast(bf16x8, wv);
                    acc = __builtin_amdgcn_mfma_f32_16x16x32_bf16(wf, nd[s], acc, 0, 0, 0);
                }
                float h0 = acc[0] + cR[t][0], h1 = acc[1] + cR[t][1];
                float h2 = acc[2] + cR[t][2], h3 = acc[3] + cR[t][3];
                h0 = h0 > 0.f ? h0 : 0.f;  h1 = h1 > 0.f ? h1 : 0.f;
                h2 = h2 > 0.f ? h2 : 0.f;  h3 = h3 > 0.f ? h3 : 0.f;
                sr += h0 * wR[t][0] + h1 * wR[t][1] + h2 * wR[t][2] + h3 * wR[t][3];
            }

            // sum across the 4 g-groups (lanes differing in bits 4,5)
            sr += __shfl_xor(sr, 16, 64);
            sr += __shfl_xor(sr, 32, 64);

            // lanes 0..15 store 16 contiguous dwords (64B per wave)
            if (lane < 16) {
                const int o = c * 16 + lane;
                if (o < n) tout[o] = sr + bias2;
            }

            unsigned char* tmp = p0; p0 = p1; p1 = tmp;
        }
    }
#undef STAGE
}

extern "C" void kernel_launch(void* const* d_in, const int* in_sizes, int n_in,
                              void* d_out, int out_size, void* d_ws, size_t ws_size,
                              hipStream_t stream) {
    const float* node_hidden = (const float*)d_in[0];
    const float* h_glob      = (const float*)d_in[1];
    const float* state       = (const float*)d_in[2];
    const float* validity    = (const float*)d_in[3];
    const float* W_hl1 = (const float*)d_in[4];  const float* b_hl1 = (const float*)d_in[5];
    const float* W_hl2 = (const float*)d_in[6];  const float* b_hl2 = (const float*)d_in[7];
    const float* W_in1 = (const float*)d_in[8];  const float* b_in1 = (const float*)d_in[9];
    const float* W_in2 = (const float*)d_in[10]; const float* b_in2 = (const float*)d_in[11];
    const float* W_ex1 = (const float*)d_in[12]; const float* b_ex1 = (const float*)d_in[13];
    const float* W_ex2 = (const float*)d_in[14]; const float* b_ex2 = (const float*)d_in[15];
    const float* W_tp1 = (const float*)d_in[16]; const float* b_tp1 = (const float*)d_in[17];
    const float* W_tp2 = (const float*)d_in[18]; const float* b_tp2 = (const float*)d_in[19];

    float* out = (float*)d_out;
    const int n = in_sizes[0] / HID;   // 400000

    teleport_kernel<<<TP_BLOCKS, TP_THREADS, 0, stream>>>(node_hidden, h_glob, state, validity,
                                                          W_hl1, b_hl1, W_hl2, b_hl2,
                                                          W_in1, b_in1, W_in2, b_in2,
                                                          W_ex1, b_ex1, W_ex2, b_ex2,
                                                          W_tp1, b_tp1, W_tp2, b_tp2,
                                                          out, n);
}